// Round 7
// baseline (43.558 us; speedup 1.0000x reference)
//
#include <hip/hip_runtime.h>
#include <hip/hip_bf16.h>
#include <math.h>

#define TT 2048
#define HH 512   // hidden = NUM_HEADS*DIM_KEY
#define NH 8
#define DK 64
#define WIN 16
#define NC 33    // 2*WIN+1

typedef __attribute__((ext_vector_type(8))) short bf16x8;
typedef __attribute__((ext_vector_type(4))) float f32x4;

__device__ inline ushort f2bf(float f) {   // RNE float -> bf16 bits
  uint u = __builtin_bit_cast(uint, f);
  return (ushort)((u + 0x7FFFu + ((u >> 16) & 1u)) >> 16);
}
__device__ inline ushort cvt1(float f) {   // compiler cast (v_cvt_pk capable)
  __hip_bfloat16 h = __float2bfloat16(f);
  return __builtin_bit_cast(ushort, h);
}

// ---------------- W fp32 -> bf16 pre-convert (weights only, 2 MB) ---------
__global__ __launch_bounds__(256) void cvt_w(
    const float* __restrict__ Wq, const float* __restrict__ Wk,
    ushort* __restrict__ Wqb, ushort* __restrict__ Wkb)
{
  const int id = blockIdx.x * 256 + threadIdx.x;   // 65536 tasks x 8 elems
  const float* src = (id < 32768) ? Wq : Wk;
  ushort* dst = (id < 32768) ? Wqb : Wkb;
  const int off = (id & 32767) * 8;
  float4 x = *(const float4*)(src + off);
  float4 y = *(const float4*)(src + off + 4);
  union { ushort s[8]; uint4 v; } pk;
  pk.s[0]=cvt1(x.x); pk.s[1]=cvt1(x.y); pk.s[2]=cvt1(x.z); pk.s[3]=cvt1(x.w);
  pk.s[4]=cvt1(y.x); pk.s[5]=cvt1(y.y); pk.s[6]=cvt1(y.z); pk.s[7]=cvt1(y.w);
  *(uint4*)(dst + off) = pk.v;
}

// -------- projection GEMM: C[M,512] = A[M,512] @ W[512,512]^T + b ---------
// Block owns BM=64 rows x FULL N=512 (8 waves, wave tile 64x64), BK=64.
// A loaded fp32 + converted in-kernel EXACTLY ONCE per element (BN spans N).
// W (bf16 pre-converted) staged via global_load_lds width-16.
// blockIdx.y selects (query,Wq,bq,Qp) vs (key,Wk,bk,Kp).
#define PBM 64
#define PBK 64

__global__ __launch_bounds__(512) void proj_fused(
    const float* __restrict__ Aq, const float* __restrict__ Ak,
    const ushort* __restrict__ Wqb, const ushort* __restrict__ Wkb,
    const float* __restrict__ bq, const float* __restrict__ bk,
    ushort* __restrict__ Qp, ushort* __restrict__ Kp)
{
  __shared__ ushort As[PBM * PBK];   // 8 KB
  __shared__ ushort Ws[HH * PBK];    // 64 KB

  const int z = blockIdx.y;
  const float*  A    = z ? Ak  : Aq;
  const ushort* Wb   = z ? Wkb : Wqb;
  const float*  bias = z ? bk  : bq;
  ushort*       C    = z ? Kp  : Qp;

  const int m0 = blockIdx.x * PBM;
  const int t  = threadIdx.x;
  const int l  = t & 63;
  const int w  = t >> 6;          // wave 0..7 -> col block w*64
  const int lr = l & 15;
  const int hi = l >> 4;
  const int lk8 = hi * 8;

  f32x4 acc[4][4] = {};

  for (int k0 = 0; k0 < HH; k0 += PBK) {
    // ---- W: 512x64 bf16 = 64 KB, 8 global_load_lds issues (16 B/lane) ----
#pragma unroll
    for (int p = 0; p < 8; ++p) {
      const int u = p * 512 + t;           // chunk 0..4095 (8 ushorts each)
      const int r = u >> 3, c8 = u & 7;
      __builtin_amdgcn_global_load_lds(
          (const __attribute__((address_space(1))) uint*)
              (Wb + (size_t)r * HH + k0 + c8 * 8),
          (__attribute__((address_space(3))) uint*)(Ws + p * 4096 + w * 512),
          16, 0, 0);
    }
    // ---- A: 64x64 fp32 -> bf16, one 8-elem chunk per thread ----
    {
      const int r = t >> 3, c8 = t & 7;
      const float* g = A + (size_t)(m0 + r) * HH + k0 + c8 * 8;
      float4 x = ((const float4*)g)[0], y = ((const float4*)g)[1];
      union { ushort s[8]; uint4 v; } pk;
      pk.s[0]=cvt1(x.x); pk.s[1]=cvt1(x.y); pk.s[2]=cvt1(x.z); pk.s[3]=cvt1(x.w);
      pk.s[4]=cvt1(y.x); pk.s[5]=cvt1(y.y); pk.s[6]=cvt1(y.z); pk.s[7]=cvt1(y.w);
      *(uint4*)&As[t * 8] = pk.v;
    }
    __syncthreads();

#pragma unroll
    for (int kk = 0; kk < PBK; kk += 32) {
      bf16x8 af[4], bf[4];
#pragma unroll
      for (int m = 0; m < 4; ++m)
        af[m] = *(const bf16x8*)&As[(m * 16 + lr) * PBK + kk + lk8];
#pragma unroll
      for (int n = 0; n < 4; ++n)
        bf[n] = *(const bf16x8*)&Ws[(w * 64 + n * 16 + lr) * PBK + kk + lk8];
#pragma unroll
      for (int m = 0; m < 4; ++m)
#pragma unroll
        for (int n = 0; n < 4; ++n)
          acc[m][n] = __builtin_amdgcn_mfma_f32_16x16x32_bf16(af[m], bf[n], acc[m][n], 0, 0, 0);
    }
    __syncthreads();
  }

  // ---- epilogue: D row=(l>>4)*4+q, col=l&15 (rounds 3-6 verified) ----
#pragma unroll
  for (int n = 0; n < 4; ++n) {
    const int col = w * 64 + n * 16 + lr;
    const float bc = bias[col];
#pragma unroll
    for (int m = 0; m < 4; ++m) {
      const int rbase = m0 + m * 16 + hi * 4;
#pragma unroll
      for (int q = 0; q < 4; ++q)
        C[(size_t)(rbase + q) * HH + col] = f2bf(acc[m][n][q] + bc);
    }
  }
}

// ---------------- MFMA windowed attention + softmax + gather --------------
// One wave per (16-row tile, head); S[16][48] via 6 MFMAs, fragments direct
// from global; in-register softmax; scatter to gathered layout.
__global__ __launch_bounds__(256) void attn_mfma(
    const ushort* __restrict__ Q, const ushort* __restrict__ Kp,
    float* __restrict__ out)
{
  const int gw = blockIdx.x * 4 + (threadIdx.x >> 6);   // 0..4095
  const int h = gw & 7;
  const int tile = gw >> 3;          // 0..511
  const int b = tile >> 7;           // 128 row-tiles per batch
  const int i0 = (tile & 127) * 16;
  const int l = threadIdx.x & 63;
  const int lo = l & 15;             // fragment row/col lane index
  const int hi = l >> 4;             // k-slice / acc row-group

  int jb = i0 - WIN;                 // start(i0) = clip(i0-16,0,T-33)
  if (jb < 0) jb = 0;
  if (jb > TT - NC) jb = TT - NC;

  const size_t qbase = ((size_t)(b * TT + i0 + lo)) * HH + h * DK + hi * 8;
  bf16x8 aq0 = *(const bf16x8*)(Q + qbase);
  bf16x8 aq1 = *(const bf16x8*)(Q + qbase + 32);

  f32x4 acc[3] = {};
#pragma unroll
  for (int a = 0; a < 3; ++a) {
    int j = jb + a * 16 + lo;
    if (j > TT - 1) j = TT - 1;      // clamped loads get masked below
    const size_t kbase = ((size_t)(b * TT + j)) * HH + h * DK + hi * 8;
    bf16x8 bk0 = *(const bf16x8*)(Kp + kbase);
    bf16x8 bk1 = *(const bf16x8*)(Kp + kbase + 32);
    acc[a] = __builtin_amdgcn_mfma_f32_16x16x32_bf16(aq0, bk0, acc[a], 0, 0, 0);
    acc[a] = __builtin_amdgcn_mfma_f32_16x16x32_bf16(aq1, bk1, acc[a], 0, 0, 0);
  }

  float e[3][4];
  float inv[4];
#pragma unroll
  for (int q = 0; q < 4; ++q) {
    const int i = i0 + hi * 4 + q;
    const int j0 = jb + lo, j1 = j0 + 16, j2 = j0 + 32;
    float s0 = (j0 >= i - WIN && j0 <= i + WIN && j0 < TT) ? acc[0][q] * 0.125f : -INFINITY;
    float s1 = (j1 >= i - WIN && j1 <= i + WIN && j1 < TT) ? acc[1][q] * 0.125f : -INFINITY;
    float s2 = (j2 >= i - WIN && j2 <= i + WIN && j2 < TT) ? acc[2][q] * 0.125f : -INFINITY;
    float m = fmaxf(fmaxf(s0, s1), s2);
#pragma unroll
    for (int off = 8; off; off >>= 1) m = fmaxf(m, __shfl_xor(m, off));
    const float e0 = __expf(s0 - m);
    const float e1 = __expf(s1 - m);
    const float e2 = __expf(s2 - m);
    e[0][q] = e0; e[1][q] = e1; e[2][q] = e2;
    float sum = e0 + e1 + e2;
#pragma unroll
    for (int off = 8; off; off >>= 1) sum += __shfl_xor(sum, off);
    inv[q] = 1.0f / sum;
  }

  const size_t obase = ((size_t)(b * NH + h)) * TT * NC;
#pragma unroll
  for (int q = 0; q < 4; ++q) {
    const int i = i0 + hi * 4 + q;
    int st = i - WIN;
    if (st < 0) st = 0;
    if (st > TT - NC) st = TT - NC;
#pragma unroll
    for (int a = 0; a < 3; ++a) {
      const int c = jb + a * 16 + lo - st;
      if (c >= 0 && c < NC)
        out[obase + (size_t)i * NC + c] = e[a][q] * inv[q];
    }
  }
}

extern "C" void kernel_launch(void* const* d_in, const int* in_sizes, int n_in,
                              void* d_out, int out_size, void* d_ws, size_t ws_size,
                              hipStream_t stream)
{
  const float* query = (const float*)d_in[0];
  const float* key   = (const float*)d_in[1];
  const float* Wq    = (const float*)d_in[2];
  const float* bq    = (const float*)d_in[3];
  const float* Wk    = (const float*)d_in[4];
  const float* bk    = (const float*)d_in[5];
  float* out = (float*)d_out;

  const int B = 4, M = B * TT;      // 8192 rows
  ushort* Wqb = (ushort*)d_ws;                  // 512x512 bf16
  ushort* Wkb = Wqb + (size_t)HH * HH;
  ushort* Qp  = Wkb + (size_t)HH * HH;          // [M,512] bf16 projected
  ushort* Kp  = Qp + (size_t)M * HH;

  cvt_w<<<dim3(256), 256, 0, stream>>>(Wq, Wk, Wqb, Wkb);
  proj_fused<<<dim3(M / PBM, 2), 512, 0, stream>>>(
      query, key, Wqb, Wkb, bq, bk, Qp, Kp);
  attn_mfma<<<dim3((M / 16) * NH / 4), 256, 0, stream>>>(Qp, Kp, out);
}

// Round 8
// 35.569 us; speedup vs baseline: 1.2246x; 1.2246x over previous
//
#include <hip/hip_runtime.h>
#include <hip/hip_bf16.h>
#include <math.h>

#define TT 2048
#define HH 512   // hidden = NUM_HEADS*DIM_KEY
#define NH 8
#define DK 64
#define WIN 16
#define NC 33    // 2*WIN+1

typedef __attribute__((ext_vector_type(8))) short bf16x8;
typedef __attribute__((ext_vector_type(4))) float f32x4;

__device__ inline ushort f2bf(float f) {   // RNE float -> bf16 bits
  uint u = __builtin_bit_cast(uint, f);
  return (ushort)((u + 0x7FFFu + ((u >> 16) & 1u)) >> 16);
}
__device__ inline ushort cvt1(float f) {   // compiler cast (v_cvt_pk capable)
  __hip_bfloat16 h = __float2bfloat16(f);
  return __builtin_bit_cast(ushort, h);
}

// ---------------- W fp32 -> bf16 pre-convert (weights only, 2 MB) ---------
__global__ __launch_bounds__(256) void cvt_w(
    const float* __restrict__ Wq, const float* __restrict__ Wk,
    ushort* __restrict__ Wqb, ushort* __restrict__ Wkb)
{
  const int id = blockIdx.x * 256 + threadIdx.x;   // 65536 tasks x 8 elems
  const float* src = (id < 32768) ? Wq : Wk;
  ushort* dst = (id < 32768) ? Wqb : Wkb;
  const int off = (id & 32767) * 8;
  float4 x = *(const float4*)(src + off);
  float4 y = *(const float4*)(src + off + 4);
  union { ushort s[8]; uint4 v; } pk;
  pk.s[0]=cvt1(x.x); pk.s[1]=cvt1(x.y); pk.s[2]=cvt1(x.z); pk.s[3]=cvt1(x.w);
  pk.s[4]=cvt1(y.x); pk.s[5]=cvt1(y.y); pk.s[6]=cvt1(y.z); pk.s[7]=cvt1(y.w);
  *(uint4*)(dst + off) = pk.v;
}

// ---------------- projection GEMM (bf16 MFMA): C = A @ W^T + b, bf16 out --
// Round-5 structure + T2 XOR swizzle (kills the 16-way bank conflict of
// 128B-stride rows). 16B-granule swizzle: LDS granule (r, gd) holds global
// column granule g = gd ^ (r&7). A reg-staged (swizzled SOURCE, linear
// ds_write); W via global_load_lds (pre-swizzled global address, linear
// LDS dest — rule #21). Fragment reads XOR the same way.
#define PBM 128
#define PBN 128
#define PBK 64

__global__ __launch_bounds__(256) void proj_mfma(
    const float* __restrict__ Aq, const float* __restrict__ Ak,
    const ushort* __restrict__ Wqb, const ushort* __restrict__ Wkb,
    const float* __restrict__ bq, const float* __restrict__ bk,
    ushort* __restrict__ Qp, ushort* __restrict__ Kp)
{
  __shared__ ushort As[PBM * PBK];   // 16 KB
  __shared__ ushort Ws[PBN * PBK];   // 16 KB

  const int z = blockIdx.z;
  const float*  A    = z ? Ak  : Aq;
  const ushort* Wb   = z ? Wkb : Wqb;
  const float*  bias = z ? bk  : bq;
  ushort*       C    = z ? Kp  : Qp;

  const int m0 = blockIdx.x * PBM;
  const int n0 = blockIdx.y * PBN;
  const int t  = threadIdx.x;
  const int l  = t & 63;
  const int w  = t >> 6;
  const int wr = (w >> 1) * 64;   // wave row offset
  const int wc = (w & 1) * 64;    // wave col offset
  const int lr = l & 15;
  const int hi = l >> 4;
  const int swz = lr & 7;         // fragment-row swizzle key

  f32x4 acc[4][4] = {};

  for (int k0 = 0; k0 < HH; k0 += PBK) {
    // ---- W: global_load_lds, source granule pre-swizzled ----
#pragma unroll
    for (int p = 0; p < 4; ++p) {
      const int u = p * 256 + t;            // LDS granule 0..1023
      const int r = u >> 3;
      const int g = (u & 7) ^ (r & 7);      // global column granule
      __builtin_amdgcn_global_load_lds(
          (const __attribute__((address_space(1))) uint*)
              (Wb + (size_t)(n0 + r) * HH + k0 + g * 8),
          (__attribute__((address_space(3))) uint*)(Ws + p * 2048 + w * 512),
          16, 0, 0);
    }
    // ---- A: reg-stage fp32 -> bf16, swizzled source, linear ds_write ----
#pragma unroll
    for (int p = 0; p < 4; ++p) {
      const int u = p * 256 + t;
      const int r = u >> 3;
      const int g = (u & 7) ^ (r & 7);
      const float* gp = A + (size_t)(m0 + r) * HH + k0 + g * 8;
      float4 x = ((const float4*)gp)[0], y = ((const float4*)gp)[1];
      union { ushort s[8]; uint4 v; } pk;
      pk.s[0]=cvt1(x.x); pk.s[1]=cvt1(x.y); pk.s[2]=cvt1(x.z); pk.s[3]=cvt1(x.w);
      pk.s[4]=cvt1(y.x); pk.s[5]=cvt1(y.y); pk.s[6]=cvt1(y.z); pk.s[7]=cvt1(y.w);
      *(uint4*)&As[u * 8] = pk.v;           // linear dest: granule u
    }
    __syncthreads();

#pragma unroll
    for (int kk = 0; kk < PBK; kk += 32) {
      const int gq = (kk >> 3) + hi;        // needed column granule
      bf16x8 af[4], bf[4];
#pragma unroll
      for (int m = 0; m < 4; ++m)
        af[m] = *(const bf16x8*)&As[(wr + m * 16 + lr) * PBK + ((gq ^ swz) * 8)];
#pragma unroll
      for (int n = 0; n < 4; ++n)
        bf[n] = *(const bf16x8*)&Ws[(wc + n * 16 + lr) * PBK + ((gq ^ swz) * 8)];
#pragma unroll
      for (int m = 0; m < 4; ++m)
#pragma unroll
        for (int n = 0; n < 4; ++n)
          acc[m][n] = __builtin_amdgcn_mfma_f32_16x16x32_bf16(af[m], bf[n], acc[m][n], 0, 0, 0);
    }
    __syncthreads();
  }

  // ---- epilogue: D row=(l>>4)*4+q, col=l&15 (rounds 3-7 verified) ----
#pragma unroll
  for (int n = 0; n < 4; ++n) {
    const int col = n0 + wc + n * 16 + lr;
    const float bc = bias[col];
#pragma unroll
    for (int m = 0; m < 4; ++m) {
      const int rbase = m0 + wr + m * 16 + hi * 4;
#pragma unroll
      for (int q = 0; q < 4; ++q)
        C[(size_t)(rbase + q) * HH + col] = f2bf(acc[m][n][q] + bc);
    }
  }
}

// ---------------- MFMA windowed attention + softmax + gather --------------
// One wave per (16-row tile, head); S[16][48] via 6 MFMAs, fragments direct
// from global; in-register softmax; scatter to gathered layout.
__global__ __launch_bounds__(256) void attn_mfma(
    const ushort* __restrict__ Q, const ushort* __restrict__ Kp,
    float* __restrict__ out)
{
  const int gw = blockIdx.x * 4 + (threadIdx.x >> 6);   // 0..4095
  const int h = gw & 7;
  const int tile = gw >> 3;          // 0..511
  const int b = tile >> 7;           // 128 row-tiles per batch
  const int i0 = (tile & 127) * 16;
  const int l = threadIdx.x & 63;
  const int lo = l & 15;             // fragment row/col lane index
  const int hi = l >> 4;             // k-slice / acc row-group

  int jb = i0 - WIN;                 // start(i0) = clip(i0-16,0,T-33)
  if (jb < 0) jb = 0;
  if (jb > TT - NC) jb = TT - NC;

  const size_t qbase = ((size_t)(b * TT + i0 + lo)) * HH + h * DK + hi * 8;
  bf16x8 aq0 = *(const bf16x8*)(Q + qbase);
  bf16x8 aq1 = *(const bf16x8*)(Q + qbase + 32);

  f32x4 acc[3] = {};
#pragma unroll
  for (int a = 0; a < 3; ++a) {
    int j = jb + a * 16 + lo;
    if (j > TT - 1) j = TT - 1;      // clamped loads get masked below
    const size_t kbase = ((size_t)(b * TT + j)) * HH + h * DK + hi * 8;
    bf16x8 bk0 = *(const bf16x8*)(Kp + kbase);
    bf16x8 bk1 = *(const bf16x8*)(Kp + kbase + 32);
    acc[a] = __builtin_amdgcn_mfma_f32_16x16x32_bf16(aq0, bk0, acc[a], 0, 0, 0);
    acc[a] = __builtin_amdgcn_mfma_f32_16x16x32_bf16(aq1, bk1, acc[a], 0, 0, 0);
  }

  float e[3][4];
  float inv[4];
#pragma unroll
  for (int q = 0; q < 4; ++q) {
    const int i = i0 + hi * 4 + q;
    const int j0 = jb + lo, j1 = j0 + 16, j2 = j0 + 32;
    float s0 = (j0 >= i - WIN && j0 <= i + WIN && j0 < TT) ? acc[0][q] * 0.125f : -INFINITY;
    float s1 = (j1 >= i - WIN && j1 <= i + WIN && j1 < TT) ? acc[1][q] * 0.125f : -INFINITY;
    float s2 = (j2 >= i - WIN && j2 <= i + WIN && j2 < TT) ? acc[2][q] * 0.125f : -INFINITY;
    float m = fmaxf(fmaxf(s0, s1), s2);
#pragma unroll
    for (int off = 8; off; off >>= 1) m = fmaxf(m, __shfl_xor(m, off));
    const float e0 = __expf(s0 - m);
    const float e1 = __expf(s1 - m);
    const float e2 = __expf(s2 - m);
    e[0][q] = e0; e[1][q] = e1; e[2][q] = e2;
    float sum = e0 + e1 + e2;
#pragma unroll
    for (int off = 8; off; off >>= 1) sum += __shfl_xor(sum, off);
    inv[q] = 1.0f / sum;
  }

  const size_t obase = ((size_t)(b * NH + h)) * TT * NC;
#pragma unroll
  for (int q = 0; q < 4; ++q) {
    const int i = i0 + hi * 4 + q;
    int st = i - WIN;
    if (st < 0) st = 0;
    if (st > TT - NC) st = TT - NC;
#pragma unroll
    for (int a = 0; a < 3; ++a) {
      const int c = jb + a * 16 + lo - st;
      if (c >= 0 && c < NC)
        out[obase + (size_t)i * NC + c] = e[a][q] * inv[q];
    }
  }
}

extern "C" void kernel_launch(void* const* d_in, const int* in_sizes, int n_in,
                              void* d_out, int out_size, void* d_ws, size_t ws_size,
                              hipStream_t stream)
{
  const float* query = (const float*)d_in[0];
  const float* key   = (const float*)d_in[1];
  const float* Wq    = (const float*)d_in[2];
  const float* bq    = (const float*)d_in[3];
  const float* Wk    = (const float*)d_in[4];
  const float* bk    = (const float*)d_in[5];
  float* out = (float*)d_out;

  const int B = 4, M = B * TT;      // 8192 rows
  ushort* Wqb = (ushort*)d_ws;                  // 512x512 bf16
  ushort* Wkb = Wqb + (size_t)HH * HH;
  ushort* Qp  = Wkb + (size_t)HH * HH;          // [M,512] bf16 projected
  ushort* Kp  = Qp + (size_t)M * HH;

  cvt_w<<<dim3(256), 256, 0, stream>>>(Wq, Wk, Wqb, Wkb);
  proj_mfma<<<dim3(M / PBM, HH / PBN, 2), 256, 0, stream>>>(
      query, key, Wqb, Wkb, bq, bk, Qp, Kp);
  attn_mfma<<<dim3((M / 16) * NH / 4), 256, 0, stream>>>(Qp, Kp, out);
}